// Round 2
// baseline (542.244 us; speedup 1.0000x reference)
//
#include <hip/hip_runtime.h>

// Problem constants: B=4, T=2048, C=1024, H=16, HD=64
#define TT 2048
#define CC 1024
#define HH 16
#define HD 64

typedef __bf16 bf16x8 __attribute__((ext_vector_type(8)));
typedef float f32x4 __attribute__((ext_vector_type(4)));

using as1_cvoid = __attribute__((address_space(1))) const void;
using as3_void  = __attribute__((address_space(3))) void;

__device__ __forceinline__ unsigned short f2bf(float f) {
  __bf16 b = (__bf16)f;
  return __builtin_bit_cast(unsigned short, b);
}

__device__ __forceinline__ void gload_lds16(const void* g, void* l) {
  __builtin_amdgcn_global_load_lds((as1_cvoid*)g, (as3_void*)l, 16, 0, 0);
}

// ---------------- cast f32 -> bf16 ----------------
__global__ void castk(const float* __restrict__ s, unsigned short* __restrict__ d, int n) {
  int i = (blockIdx.x * blockDim.x + threadIdx.x) * 4;
  if (i < n) {
    float4 v = *reinterpret_cast<const float4*>(s + i);
    ushort4 o;
    o.x = f2bf(v.x); o.y = f2bf(v.y); o.z = f2bf(v.z); o.w = f2bf(v.w);
    *reinterpret_cast<ushort4*>(d + i) = o;
  }
}

// ---------------- GEMM: C[M,N] = A[M,K] @ B[N,K]^T (bf16 in, bf16/f32 out) ----
#define BM 128
#define BN 128
#define BK 64

// stage a 128x64 bf16 tile into LDS with XOR-swizzle (g ^= row&7) applied by
// pre-swizzling the GLOBAL source address (LDS dest stays lane-linear).
__device__ __forceinline__ void stage128x64(const unsigned short* __restrict__ src,
                                            int ld, char* ldsbase, int tid) {
#pragma unroll
  for (int it = 0; it < 4; ++it) {
    int j = it * 256 + tid;          // 16B block index, 1024 total
    int row = j >> 3;                // 8 blocks per 128B row
    int lg = (j & 7) ^ (row & 7);    // logical k-group to fetch
    const unsigned short* g = src + row * ld + lg * 8;
    gload_lds16(g, ldsbase + j * 16);
  }
}

template <int OUTF32>
__global__ __launch_bounds__(256)
void gemm_bt(const unsigned short* __restrict__ A, const unsigned short* __restrict__ B,
             void* __restrict__ Cout, int M, int N, int K) {
  __shared__ char lds[2][2 * BM * BK * 2];  // [buf][A 16KB | B 16KB]
  const int tid = threadIdx.x;
  const int lane = tid & 63;
  const int w = tid >> 6;
  const int wr = w >> 1, wc = w & 1;
  const int l15 = lane & 15, l4 = lane >> 4;

  const int rowA0 = blockIdx.x * BM;
  const int colB0 = blockIdx.y * BN;

  f32x4 acc[4][4] = {};

  const unsigned short* Abase = A + (size_t)rowA0 * K;
  const unsigned short* Bbase = B + (size_t)colB0 * K;

  int a_off[2][4], b_off[2][4];
#pragma unroll
  for (int kk = 0; kk < 2; ++kk)
#pragma unroll
    for (int m = 0; m < 4; ++m) {
      int row = wr * 64 + m * 16 + l15;
      int g = kk * 4 + l4;
      a_off[kk][m] = row * 128 + ((g ^ (row & 7)) * 16);
      int rowb = wc * 64 + m * 16 + l15;
      b_off[kk][m] = rowb * 128 + ((g ^ (rowb & 7)) * 16);
    }

  const int NT = K / BK;
  stage128x64(Abase, K, &lds[0][0], tid);
  stage128x64(Bbase, K, &lds[0][BM * BK * 2], tid);
  asm volatile("s_waitcnt vmcnt(0)" ::: "memory");
  __syncthreads();

  int buf = 0;
  for (int t = 0; t < NT; ++t) {
    if (t + 1 < NT) {
      stage128x64(Abase + (t + 1) * BK, K, &lds[buf ^ 1][0], tid);
      stage128x64(Bbase + (t + 1) * BK, K, &lds[buf ^ 1][BM * BK * 2], tid);
    }
    const char* aLds = &lds[buf][0];
    const char* bLds = &lds[buf][BM * BK * 2];
#pragma unroll
    for (int kk = 0; kk < 2; ++kk) {
      bf16x8 af[4], bfv[4];
#pragma unroll
      for (int m = 0; m < 4; ++m) af[m] = *reinterpret_cast<const bf16x8*>(aLds + a_off[kk][m]);
#pragma unroll
      for (int n = 0; n < 4; ++n) bfv[n] = *reinterpret_cast<const bf16x8*>(bLds + b_off[kk][n]);
#pragma unroll
      for (int m = 0; m < 4; ++m)
#pragma unroll
        for (int n = 0; n < 4; ++n)
          acc[m][n] = __builtin_amdgcn_mfma_f32_16x16x32_bf16(af[m], bfv[n], acc[m][n], 0, 0, 0);
    }
    asm volatile("s_waitcnt vmcnt(0)" ::: "memory");
    __syncthreads();
    buf ^= 1;
  }

#pragma unroll
  for (int m = 0; m < 4; ++m) {
#pragma unroll
    for (int r = 0; r < 4; ++r) {
      int row = rowA0 + wr * 64 + m * 16 + l4 * 4 + r;
#pragma unroll
      for (int n = 0; n < 4; ++n) {
        int col = colB0 + wc * 64 + n * 16 + l15;
        if (OUTF32)
          reinterpret_cast<float*>(Cout)[(size_t)row * N + col] = acc[m][n][r];
        else
          reinterpret_cast<unsigned short*>(Cout)[(size_t)row * N + col] = f2bf(acc[m][n][r]);
      }
    }
  }
}

// ---------------- causal flash attention ----------------
// grid: (32 qblocks of 64 rows, B*H). block: 256 threads, wave w owns 16 q-rows.
__global__ __launch_bounds__(256)
void attn(const unsigned short* __restrict__ Q, const unsigned short* __restrict__ Kmat,
          const unsigned short* __restrict__ V, unsigned short* __restrict__ O) {
  __shared__ char smem[24576];  // Ks 8KB | Vt 8KB | Pw 4x2KB
  const int tid = threadIdx.x, lane = tid & 63, w = tid >> 6;
  const int l15 = lane & 15, l4 = lane >> 4;
  const int qblock = blockIdx.x;
  const int bh = blockIdx.y;
  const int b = bh >> 4, h = bh & 15;
  const size_t bT = (size_t)b * TT;
  const int qbase = qblock * 64;
  const int q0 = qbase + w * 16;

  // Q fragments (A-operand): row = l15, k = kk*32 + l4*8 + j
  const unsigned short* qp = Q + (bT + q0 + l15) * CC + h * HD;
  bf16x8 qf[2];
  qf[0] = *reinterpret_cast<const bf16x8*>(qp + l4 * 8);
  qf[1] = *reinterpret_cast<const bf16x8*>(qp + 32 + l4 * 8);

  f32x4 o[4] = {};
  float mrun[4], lrun[4];
#pragma unroll
  for (int r = 0; r < 4; ++r) { mrun[r] = -1e30f; lrun[r] = 0.f; }

  char* Ks = smem;
  char* Vt = smem + 8192;
  char* Pw = smem + 16384 + w * 2048;

  int koff[4][2], poff[2];
#pragma unroll
  for (int n = 0; n < 4; ++n)
#pragma unroll
    for (int kk = 0; kk < 2; ++kk) {
      int row = n * 16 + l15;
      int g = kk * 4 + l4;
      koff[n][kk] = row * 128 + ((g ^ (row & 7)) * 16);
    }
#pragma unroll
  for (int kk = 0; kk < 2; ++kk) {
    int row = l15;
    int g = kk * 4 + l4;
    poff[kk] = row * 128 + ((g ^ (row & 7)) * 16);
  }

  const float sc = 0.125f;          // HD^-0.5
  const float LOG2E = 1.44269504f;

  for (int t = 0; t <= qblock; ++t) {
    const int kb0 = t * 64;
    __syncthreads();  // prior iteration done reading Ks/Vt
    // stage K tile [64 keys][64 d], swizzled, via global_load_lds
#pragma unroll
    for (int it = 0; it < 2; ++it) {
      int j = it * 256 + tid;
      int row = j >> 3;
      int lg = (j & 7) ^ (row & 7);
      const unsigned short* g = Kmat + (bT + kb0 + row) * CC + h * HD + lg * 8;
      gload_lds16(g, Ks + j * 16);
    }
    // stage V transposed: Vt[d][key] (swizzled rows of 64 keys)
#pragma unroll
    for (int it = 0; it < 2; ++it) {
      int j = it * 256 + tid;
      int key = j >> 3;
      int d0 = (j & 7) * 8;
      bf16x8 vv = *reinterpret_cast<const bf16x8*>(V + (bT + kb0 + key) * CC + h * HD + d0);
#pragma unroll
      for (int jj = 0; jj < 8; ++jj) {
        int row = d0 + jj;
        int gq = key >> 3;
        int off = row * 128 + ((gq ^ (row & 7)) * 16) + (key & 7) * 2;
        *reinterpret_cast<__bf16*>(Vt + off) = vv[jj];
      }
    }
    asm volatile("s_waitcnt vmcnt(0)" ::: "memory");
    __syncthreads();

    // S = Q K^T : s[n] covers keys n*16+l15, rows l4*4+r
    f32x4 s[4] = {};
#pragma unroll
    for (int n = 0; n < 4; ++n)
#pragma unroll
      for (int kk = 0; kk < 2; ++kk) {
        bf16x8 kf = *reinterpret_cast<const bf16x8*>(Ks + koff[n][kk]);
        s[n] = __builtin_amdgcn_mfma_f32_16x16x32_bf16(qf[kk], kf, s[n], 0, 0, 0);
      }

    if (t == qblock) {  // diagonal tile: causal mask
#pragma unroll
      for (int n = 0; n < 4; ++n) {
        int key = kb0 + n * 16 + l15;
#pragma unroll
        for (int r = 0; r < 4; ++r) {
          int q = q0 + l4 * 4 + r;
          if (key > q) s[n][r] = -1e30f;
        }
      }
    }

    // online softmax (rows live in the 16-lane group sharing l4)
    float tm[4];
#pragma unroll
    for (int r = 0; r < 4; ++r)
      tm[r] = fmaxf(fmaxf(s[0][r], s[1][r]), fmaxf(s[2][r], s[3][r]));
#pragma unroll
    for (int off = 1; off < 16; off <<= 1)
#pragma unroll
      for (int r = 0; r < 4; ++r) tm[r] = fmaxf(tm[r], __shfl_xor(tm[r], off, 64));

    float mnew[4], alpha[4];
#pragma unroll
    for (int r = 0; r < 4; ++r) {
      mnew[r] = fmaxf(mrun[r], tm[r] * sc);
      alpha[r] = exp2f((mrun[r] - mnew[r]) * LOG2E);
      mrun[r] = mnew[r];
    }
    float ts[4] = {0.f, 0.f, 0.f, 0.f};
#pragma unroll
    for (int n = 0; n < 4; ++n)
#pragma unroll
      for (int r = 0; r < 4; ++r) {
        float p = exp2f((s[n][r] * sc - mnew[r]) * LOG2E);
        s[n][r] = p;
        ts[r] += p;
      }
#pragma unroll
    for (int off = 1; off < 16; off <<= 1)
#pragma unroll
      for (int r = 0; r < 4; ++r) ts[r] += __shfl_xor(ts[r], off, 64);
#pragma unroll
    for (int r = 0; r < 4; ++r) lrun[r] = lrun[r] * alpha[r] + ts[r];
#pragma unroll
    for (int nf2 = 0; nf2 < 4; ++nf2)
#pragma unroll
      for (int r = 0; r < 4; ++r) o[nf2][r] *= alpha[r];

    // write P (bf16) into per-wave LDS, swizzled like everything else
#pragma unroll
    for (int n = 0; n < 4; ++n)
#pragma unroll
      for (int r = 0; r < 4; ++r) {
        int row = l4 * 4 + r;
        int col = n * 16 + l15;
        int gq = col >> 3;
        int off = row * 128 + ((gq ^ (row & 7)) * 16) + (col & 7) * 2;
        *reinterpret_cast<__bf16*>(Pw + off) = (__bf16)s[n][r];
      }

    // FENCE: the P ds_writes (scalar stores) and the pf ds_read (bf16x8 vector
    // load) don't alias under TBAA -> without this the compiler can hoist the
    // read above the writes. Memory clobber orders DS ops; sched_barrier pins
    // the machine scheduler (rule #18). Same-wave DS RAW is HW-in-order, and
    // lgkmcnt(0) makes it airtight.
    asm volatile("s_waitcnt lgkmcnt(0)" ::: "memory");
    __builtin_amdgcn_sched_barrier(0);

    // PV: o[nf2] += P @ V  (wave-private P)
#pragma unroll
    for (int kk = 0; kk < 2; ++kk) {
      bf16x8 pf = *reinterpret_cast<const bf16x8*>(Pw + poff[kk]);
#pragma unroll
      for (int nf2 = 0; nf2 < 4; ++nf2) {
        bf16x8 vf = *reinterpret_cast<const bf16x8*>(Vt + koff[nf2][kk]);
        o[nf2] = __builtin_amdgcn_mfma_f32_16x16x32_bf16(pf, vf, o[nf2], 0, 0, 0);
      }
    }
  }

  // epilogue: O[b,q, h*64+d] bf16
#pragma unroll
  for (int nf2 = 0; nf2 < 4; ++nf2)
#pragma unroll
    for (int r = 0; r < 4; ++r) {
      int q = q0 + l4 * 4 + r;
      int col = h * HD + nf2 * 16 + l15;
      float val = o[nf2][r] / lrun[r];
      O[(bT + q) * CC + col] = f2bf(val);
    }
}

// ---------------- launch ----------------
extern "C" void kernel_launch(void* const* d_in, const int* in_sizes, int n_in,
                              void* d_out, int out_size, void* d_ws, size_t ws_size,
                              hipStream_t stream) {
  const float* x  = (const float*)d_in[0];
  const float* Wq = (const float*)d_in[1];
  const float* Wk = (const float*)d_in[2];
  const float* Wv = (const float*)d_in[3];
  const float* Wo = (const float*)d_in[4];

  char* ws = (char*)d_ws;
  const size_t NX = (size_t)4 * TT * CC;       // 8388608
  const size_t NW = (size_t)CC * CC;           // 1048576
  unsigned short* xb  = (unsigned short*)(ws);
  unsigned short* qb  = (unsigned short*)(ws + 1 * NX * 2);
  unsigned short* kb  = (unsigned short*)(ws + 2 * NX * 2);
  unsigned short* vb  = (unsigned short*)(ws + 3 * NX * 2);
  unsigned short* ob  = (unsigned short*)(ws + 4 * NX * 2);
  unsigned short* wqb = (unsigned short*)(ws + 5 * NX * 2);
  unsigned short* wkb = (unsigned short*)(ws + 5 * NX * 2 + 1 * NW * 2);
  unsigned short* wvb = (unsigned short*)(ws + 5 * NX * 2 + 2 * NW * 2);
  unsigned short* wob = (unsigned short*)(ws + 5 * NX * 2 + 3 * NW * 2);

  castk<<<(int)(NX / 1024), 256, 0, stream>>>(x, xb, (int)NX);
  castk<<<(int)(NW / 1024), 256, 0, stream>>>(Wq, wqb, (int)NW);
  castk<<<(int)(NW / 1024), 256, 0, stream>>>(Wk, wkb, (int)NW);
  castk<<<(int)(NW / 1024), 256, 0, stream>>>(Wv, wvb, (int)NW);
  castk<<<(int)(NW / 1024), 256, 0, stream>>>(Wo, wob, (int)NW);

  dim3 gg(8192 / BM, CC / BN);  // 64 x 8
  gemm_bt<0><<<gg, 256, 0, stream>>>(xb, wqb, qb, 8192, CC, CC);
  gemm_bt<0><<<gg, 256, 0, stream>>>(xb, wkb, kb, 8192, CC, CC);
  gemm_bt<0><<<gg, 256, 0, stream>>>(xb, wvb, vb, 8192, CC, CC);

  attn<<<dim3(TT / 64, 4 * HH), 256, 0, stream>>>(qb, kb, vb, ob);

  gemm_bt<1><<<gg, 256, 0, stream>>>(ob, wob, d_out, 8192, CC, CC);
}

// Round 8
// 490.868 us; speedup vs baseline: 1.1047x; 1.1047x over previous
//
#include <hip/hip_runtime.h>

// Problem constants: B=4, T=2048, C=1024, H=16, HD=64
#define TT 2048
#define CC 1024
#define HH 16
#define HD 64

typedef __bf16 bf16x8 __attribute__((ext_vector_type(8)));
typedef float f32x4 __attribute__((ext_vector_type(4)));

using as1_cvoid = __attribute__((address_space(1))) const void;
using as3_void  = __attribute__((address_space(3))) void;

__device__ __forceinline__ unsigned short f2bf(float f) {
  __bf16 b = (__bf16)f;
  return __builtin_bit_cast(unsigned short, b);
}

__device__ __forceinline__ void gload_lds16(const void* g, void* l) {
  __builtin_amdgcn_global_load_lds((as1_cvoid*)g, (as3_void*)l, 16, 0, 0);
}

// ---------------- cast f32 -> bf16 ----------------
__global__ void castk(const float* __restrict__ s, unsigned short* __restrict__ d, int n) {
  int i = (blockIdx.x * blockDim.x + threadIdx.x) * 4;
  if (i < n) {
    float4 v = *reinterpret_cast<const float4*>(s + i);
    ushort4 o;
    o.x = f2bf(v.x); o.y = f2bf(v.y); o.z = f2bf(v.z); o.w = f2bf(v.w);
    *reinterpret_cast<ushort4*>(d + i) = o;
  }
}

// ---------------- GEMM: C[M,N] = A[M,K] @ B[N,K]^T (verified) ----------------
#define BM 128
#define BN 128
#define BK 64

__device__ __forceinline__ void stage128x64(const unsigned short* __restrict__ src,
                                            int ld, char* ldsbase, int tid) {
#pragma unroll
  for (int it = 0; it < 4; ++it) {
    int j = it * 256 + tid;          // 16B block index, 1024 total
    int row = j >> 3;                // 8 blocks per 128B row
    int lg = (j & 7) ^ (row & 7);    // swizzled k-group (pre-swizzle SOURCE)
    const unsigned short* g = src + row * ld + lg * 8;
    gload_lds16(g, ldsbase + j * 16);
  }
}

template <int OUTF32>
__global__ __launch_bounds__(256)
void gemm_bt(const unsigned short* __restrict__ A, const unsigned short* __restrict__ B,
             void* __restrict__ Cout, int M, int N, int K) {
  __shared__ char lds[2][2 * BM * BK * 2];  // [buf][A 16KB | B 16KB]
  const int tid = threadIdx.x;
  const int lane = tid & 63;
  const int w = tid >> 6;
  const int wr = w >> 1, wc = w & 1;
  const int l15 = lane & 15, l4 = lane >> 4;

  const int rowA0 = blockIdx.x * BM;
  const int colB0 = blockIdx.y * BN;

  f32x4 acc[4][4] = {};

  const unsigned short* Abase = A + (size_t)rowA0 * K;
  const unsigned short* Bbase = B + (size_t)colB0 * K;

  int a_off[2][4], b_off[2][4];
#pragma unroll
  for (int kk = 0; kk < 2; ++kk)
#pragma unroll
    for (int m = 0; m < 4; ++m) {
      int row = wr * 64 + m * 16 + l15;
      int g = kk * 4 + l4;
      a_off[kk][m] = row * 128 + ((g ^ (row & 7)) * 16);
      int rowb = wc * 64 + m * 16 + l15;
      b_off[kk][m] = rowb * 128 + ((g ^ (rowb & 7)) * 16);
    }

  const int NT = K / BK;
  stage128x64(Abase, K, &lds[0][0], tid);
  stage128x64(Bbase, K, &lds[0][BM * BK * 2], tid);
  asm volatile("s_waitcnt vmcnt(0)" ::: "memory");
  __syncthreads();

  int buf = 0;
  for (int t = 0; t < NT; ++t) {
    if (t + 1 < NT) {
      stage128x64(Abase + (t + 1) * BK, K, &lds[buf ^ 1][0], tid);
      stage128x64(Bbase + (t + 1) * BK, K, &lds[buf ^ 1][BM * BK * 2], tid);
    }
    const char* aLds = &lds[buf][0];
    const char* bLds = &lds[buf][BM * BK * 2];
#pragma unroll
    for (int kk = 0; kk < 2; ++kk) {
      bf16x8 af[4], bfv[4];
#pragma unroll
      for (int m = 0; m < 4; ++m) af[m] = *reinterpret_cast<const bf16x8*>(aLds + a_off[kk][m]);
#pragma unroll
      for (int n = 0; n < 4; ++n) bfv[n] = *reinterpret_cast<const bf16x8*>(bLds + b_off[kk][n]);
#pragma unroll
      for (int m = 0; m < 4; ++m)
#pragma unroll
        for (int n = 0; n < 4; ++n)
          acc[m][n] = __builtin_amdgcn_mfma_f32_16x16x32_bf16(af[m], bfv[n], acc[m][n], 0, 0, 0);
    }
    asm volatile("s_waitcnt vmcnt(0)" ::: "memory");
    __syncthreads();
    buf ^= 1;
  }

#pragma unroll
  for (int m = 0; m < 4; ++m) {
#pragma unroll
    for (int r = 0; r < 4; ++r) {
      int row = rowA0 + wr * 64 + m * 16 + l4 * 4 + r;
#pragma unroll
      for (int n = 0; n < 4; ++n) {
        int col = colB0 + wc * 64 + n * 16 + l15;
        if (OUTF32)
          reinterpret_cast<float*>(Cout)[(size_t)row * N + col] = acc[m][n][r];
        else
          reinterpret_cast<unsigned short*>(Cout)[(size_t)row * N + col] = f2bf(acc[m][n][r]);
      }
    }
  }
}

// ---------------- causal flash attention ----------------
// Round-2 (verified PASS) dataflow, byte-identical per-tile body. SINGLE
// structural delta: each block covers 128 q-rows; per staged tile the verified
// body runs twice (group A = qb0+w*16, group B = qb0+64+w*16) with separate
// online-softmax state, sharing Ks/Vs/Pw. Group A skips the last (diagonal-of-B)
// tile via a wave-uniform guard placed outside all barriers.
__global__ __launch_bounds__(256)
void attn(const unsigned short* __restrict__ Q, const unsigned short* __restrict__ Kmat,
          const unsigned short* __restrict__ V, unsigned short* __restrict__ O) {
  __shared__ char smem[24576];  // Ks 8KB | VsL 8KB | Pw 4x2KB
  const int tid = threadIdx.x, lane = tid & 63, w = tid >> 6;
  const int l15 = lane & 15, l4 = lane >> 4;
  const int bx = blockIdx.x;            // [0, T/128)
  const int bh = blockIdx.y;
  const int b = bh >> 4, h = bh & 15;
  const size_t bT = (size_t)b * TT;
  const int qb0 = bx * 128;
  const int q0A = qb0 + w * 16;
  const int q0B = qb0 + 64 + w * 16;

  char* Ks = smem;
  char* VsL = smem + 8192;
  char* Pw = smem + 16384 + w * 2048;

  // Q fragments (A-operand): row = l15, k = kk*32 + l4*8 + j
  const unsigned short* qpA = Q + (bT + q0A + l15) * CC + h * HD;
  const unsigned short* qpB = Q + (bT + q0B + l15) * CC + h * HD;
  bf16x8 qfA[2], qfB[2];
  qfA[0] = *reinterpret_cast<const bf16x8*>(qpA + l4 * 8);
  qfA[1] = *reinterpret_cast<const bf16x8*>(qpA + 32 + l4 * 8);
  qfB[0] = *reinterpret_cast<const bf16x8*>(qpB + l4 * 8);
  qfB[1] = *reinterpret_cast<const bf16x8*>(qpB + 32 + l4 * 8);

  f32x4 oA[4] = {}, oB[4] = {};
  float mA[4], lA[4], mB[4], lB[4];
#pragma unroll
  for (int r = 0; r < 4; ++r) {
    mA[r] = -1e30f; lA[r] = 0.f; mB[r] = -1e30f; lB[r] = 0.f;
  }

  int koff[4][2], poff[2];
#pragma unroll
  for (int n = 0; n < 4; ++n)
#pragma unroll
    for (int kk = 0; kk < 2; ++kk) {
      int row = n * 16 + l15;
      int g = kk * 4 + l4;
      koff[n][kk] = row * 128 + ((g ^ (row & 7)) * 16);
    }
#pragma unroll
  for (int kk = 0; kk < 2; ++kk) {
    int row = l15;
    int g = kk * 4 + l4;
    poff[kk] = row * 128 + ((g ^ (row & 7)) * 16);
  }

  const float sc = 0.125f;          // HD^-0.5
  const float LOG2E = 1.44269504f;
  const int lastA = 2 * bx;         // diagonal tile index for group A
  const int lastB = 2 * bx + 1;     // diagonal tile index for group B

  // verified per-tile body (round-2, byte-identical math), parameterized on
  // group state; all indexing compile-time (rule #20).
#define TILE_BODY(QF, OO, MR, LR, Q0, ISDIAG, KB0)                               \
  {                                                                              \
    f32x4 s_[4] = {};                                                            \
    _Pragma("unroll")                                                            \
    for (int n = 0; n < 4; ++n)                                                  \
      _Pragma("unroll")                                                          \
      for (int kk = 0; kk < 2; ++kk) {                                           \
        bf16x8 kf = *reinterpret_cast<const bf16x8*>(Ks + koff[n][kk]);          \
        s_[n] = __builtin_amdgcn_mfma_f32_16x16x32_bf16(QF[kk], kf, s_[n], 0, 0, 0); \
      }                                                                          \
    if (ISDIAG) {                                                                \
      _Pragma("unroll")                                                          \
      for (int n = 0; n < 4; ++n) {                                              \
        int key = (KB0) + n * 16 + l15;                                          \
        _Pragma("unroll")                                                        \
        for (int r = 0; r < 4; ++r) {                                            \
          int q = (Q0) + l4 * 4 + r;                                             \
          if (key > q) s_[n][r] = -1e30f;                                        \
        }                                                                        \
      }                                                                          \
    }                                                                            \
    float tm_[4];                                                                \
    _Pragma("unroll")                                                            \
    for (int r = 0; r < 4; ++r)                                                  \
      tm_[r] = fmaxf(fmaxf(s_[0][r], s_[1][r]), fmaxf(s_[2][r], s_[3][r]));      \
    _Pragma("unroll")                                                            \
    for (int off = 1; off < 16; off <<= 1)                                       \
      _Pragma("unroll")                                                          \
      for (int r = 0; r < 4; ++r) tm_[r] = fmaxf(tm_[r], __shfl_xor(tm_[r], off, 64)); \
    float mnew_[4], alpha_[4];                                                   \
    _Pragma("unroll")                                                            \
    for (int r = 0; r < 4; ++r) {                                                \
      mnew_[r] = fmaxf(MR[r], tm_[r] * sc);                                      \
      alpha_[r] = exp2f((MR[r] - mnew_[r]) * LOG2E);                             \
      MR[r] = mnew_[r];                                                          \
    }                                                                            \
    float ts_[4] = {0.f, 0.f, 0.f, 0.f};                                         \
    _Pragma("unroll")                                                            \
    for (int n = 0; n < 4; ++n)                                                  \
      _Pragma("unroll")                                                          \
      for (int r = 0; r < 4; ++r) {                                              \
        float p = exp2f((s_[n][r] * sc - mnew_[r]) * LOG2E);                     \
        s_[n][r] = p;                                                            \
        ts_[r] += p;                                                             \
      }                                                                          \
    _Pragma("unroll")                                                            \
    for (int off = 1; off < 16; off <<= 1)                                       \
      _Pragma("unroll")                                                          \
      for (int r = 0; r < 4; ++r) ts_[r] += __shfl_xor(ts_[r], off, 64);         \
    _Pragma("unroll")                                                            \
    for (int r = 0; r < 4; ++r) LR[r] = LR[r] * alpha_[r] + ts_[r];              \
    _Pragma("unroll")                                                            \
    for (int nf2 = 0; nf2 < 4; ++nf2)                                            \
      _Pragma("unroll")                                                          \
      for (int r = 0; r < 4; ++r) OO[nf2][r] *= alpha_[r];                       \
    _Pragma("unroll")                                                            \
    for (int n = 0; n < 4; ++n)                                                  \
      _Pragma("unroll")                                                          \
      for (int r = 0; r < 4; ++r) {                                              \
        int row = l4 * 4 + r;                                                    \
        int col = n * 16 + l15;                                                  \
        int gq = col >> 3;                                                       \
        int off = row * 128 + ((gq ^ (row & 7)) * 16) + (col & 7) * 2;           \
        *reinterpret_cast<__bf16*>(Pw + off) = (__bf16)s_[n][r];                 \
      }                                                                          \
    asm volatile("s_waitcnt lgkmcnt(0)" ::: "memory");                           \
    __builtin_amdgcn_sched_barrier(0);                                           \
    _Pragma("unroll")                                                            \
    for (int kk = 0; kk < 2; ++kk) {                                             \
      bf16x8 pf = *reinterpret_cast<const bf16x8*>(Pw + poff[kk]);               \
      _Pragma("unroll")                                                          \
      for (int nf2 = 0; nf2 < 4; ++nf2) {                                        \
        bf16x8 vf = *reinterpret_cast<const bf16x8*>(VsL + koff[nf2][kk]);       \
        OO[nf2] = __builtin_amdgcn_mfma_f32_16x16x32_bf16(pf, vf, OO[nf2], 0, 0, 0); \
      }                                                                          \
    }                                                                            \
  }

  for (int t = 0; t <= lastB; ++t) {
    const int kb0 = t * 64;
    __syncthreads();  // prior iteration done reading Ks/VsL
    // stage K tile [64 keys][64 d], swizzled source, linear dest (round-2)
#pragma unroll
    for (int it = 0; it < 2; ++it) {
      int j = it * 256 + tid;
      int row = j >> 3;
      int lg = (j & 7) ^ (row & 7);
      const unsigned short* g = Kmat + (bT + kb0 + row) * CC + h * HD + lg * 8;
      gload_lds16(g, Ks + j * 16);
    }
    // stage V transposed in-kernel (round-2 verified path, __bf16 stores)
#pragma unroll
    for (int it = 0; it < 2; ++it) {
      int j = it * 256 + tid;
      int key = j >> 3;
      int d0 = (j & 7) * 8;
      bf16x8 vv = *reinterpret_cast<const bf16x8*>(V + (bT + kb0 + key) * CC + h * HD + d0);
#pragma unroll
      for (int jj = 0; jj < 8; ++jj) {
        int row = d0 + jj;
        int gq = key >> 3;
        int off = row * 128 + ((gq ^ (row & 7)) * 16) + (key & 7) * 2;
        *reinterpret_cast<__bf16*>(VsL + off) = vv[jj];
      }
    }
    asm volatile("s_waitcnt vmcnt(0)" ::: "memory");
    __syncthreads();

    if (t <= lastA) {  // wave-uniform (t, bx uniform); outside barriers
      TILE_BODY(qfA, oA, mA, lA, q0A, (t == lastA), kb0)
    }
    TILE_BODY(qfB, oB, mB, lB, q0B, (t == lastB), kb0)
  }
#undef TILE_BODY

  // epilogue: O[b,q, h*64+d] bf16, both groups
#pragma unroll
  for (int nf2 = 0; nf2 < 4; ++nf2)
#pragma unroll
    for (int r = 0; r < 4; ++r) {
      int col = h * HD + nf2 * 16 + l15;
      int qA = q0A + l4 * 4 + r;
      O[(bT + qA) * CC + col] = f2bf(oA[nf2][r] / lA[r]);
      int qB = q0B + l4 * 4 + r;
      O[(bT + qB) * CC + col] = f2bf(oB[nf2][r] / lB[r]);
    }
}

// ---------------- launch ----------------
extern "C" void kernel_launch(void* const* d_in, const int* in_sizes, int n_in,
                              void* d_out, int out_size, void* d_ws, size_t ws_size,
                              hipStream_t stream) {
  const float* x  = (const float*)d_in[0];
  const float* Wq = (const float*)d_in[1];
  const float* Wk = (const float*)d_in[2];
  const float* Wv = (const float*)d_in[3];
  const float* Wo = (const float*)d_in[4];

  char* ws = (char*)d_ws;
  const size_t NX = (size_t)4 * TT * CC;       // 8388608
  const size_t NW = (size_t)CC * CC;           // 1048576
  unsigned short* xb  = (unsigned short*)(ws);
  unsigned short* qb  = (unsigned short*)(ws + 1 * NX * 2);
  unsigned short* kb  = (unsigned short*)(ws + 2 * NX * 2);
  unsigned short* vb  = (unsigned short*)(ws + 3 * NX * 2);
  unsigned short* ob  = (unsigned short*)(ws + 4 * NX * 2);
  unsigned short* wqb = (unsigned short*)(ws + 5 * NX * 2);
  unsigned short* wkb = (unsigned short*)(ws + 5 * NX * 2 + 1 * NW * 2);
  unsigned short* wvb = (unsigned short*)(ws + 5 * NX * 2 + 2 * NW * 2);
  unsigned short* wob = (unsigned short*)(ws + 5 * NX * 2 + 3 * NW * 2);

  castk<<<(int)(NX / 1024), 256, 0, stream>>>(x, xb, (int)NX);
  castk<<<(int)(NW / 1024), 256, 0, stream>>>(Wq, wqb, (int)NW);
  castk<<<(int)(NW / 1024), 256, 0, stream>>>(Wk, wkb, (int)NW);
  castk<<<(int)(NW / 1024), 256, 0, stream>>>(Wv, wvb, (int)NW);
  castk<<<(int)(NW / 1024), 256, 0, stream>>>(Wo, wob, (int)NW);

  dim3 gg(8192 / BM, CC / BN);  // 64 x 8
  gemm_bt<0><<<gg, 256, 0, stream>>>(xb, wqb, qb, 8192, CC, CC);
  gemm_bt<0><<<gg, 256, 0, stream>>>(xb, wkb, kb, 8192, CC, CC);
  gemm_bt<0><<<gg, 256, 0, stream>>>(xb, wvb, vb, 8192, CC, CC);

  attn<<<dim3(TT / 128, 4 * HH), 256, 0, stream>>>(qb, kb, vb, ob);

  gemm_bt<1><<<gg, 256, 0, stream>>>(ob, wob, d_out, 8192, CC, CC);
}

// Round 9
// 364.051 us; speedup vs baseline: 1.4895x; 1.3483x over previous
//
#include <hip/hip_runtime.h>

// Problem constants: B=4, T=2048, C=1024, H=16, HD=64
#define TT 2048
#define CC 1024
#define HH 16
#define HD 64

typedef __bf16 bf16x8 __attribute__((ext_vector_type(8)));
typedef float f32x4 __attribute__((ext_vector_type(4)));

using as1_cvoid = __attribute__((address_space(1))) const void;
using as3_void  = __attribute__((address_space(3))) void;

__device__ __forceinline__ unsigned short f2bf(float f) {
  __bf16 b = (__bf16)f;
  return __builtin_bit_cast(unsigned short, b);
}

__device__ __forceinline__ void gload_lds16(const void* g, void* l) {
  __builtin_amdgcn_global_load_lds((as1_cvoid*)g, (as3_void*)l, 16, 0, 0);
}

// ---------------- cast f32 -> bf16 ----------------
__global__ void castk(const float* __restrict__ s, unsigned short* __restrict__ d, int n) {
  int i = (blockIdx.x * blockDim.x + threadIdx.x) * 4;
  if (i < n) {
    float4 v = *reinterpret_cast<const float4*>(s + i);
    ushort4 o;
    o.x = f2bf(v.x); o.y = f2bf(v.y); o.z = f2bf(v.z); o.w = f2bf(v.w);
    *reinterpret_cast<ushort4*>(d + i) = o;
  }
}

// ---------------- GEMM: C[M,N] = A[M,K] @ B[N,K]^T (verified) ----------------
#define BM 128
#define BN 128
#define BK 64

__device__ __forceinline__ void stage128x64(const unsigned short* __restrict__ src,
                                            int ld, char* ldsbase, int tid) {
#pragma unroll
  for (int it = 0; it < 4; ++it) {
    int j = it * 256 + tid;          // 16B block index, 1024 total
    int row = j >> 3;                // 8 blocks per 128B row
    int lg = (j & 7) ^ (row & 7);    // swizzled k-group (pre-swizzle SOURCE)
    const unsigned short* g = src + row * ld + lg * 8;
    gload_lds16(g, ldsbase + j * 16);
  }
}

template <int OUTF32>
__global__ __launch_bounds__(256)
void gemm_bt(const unsigned short* __restrict__ A, const unsigned short* __restrict__ B,
             void* __restrict__ Cout, int M, int N, int K) {
  __shared__ char lds[2][2 * BM * BK * 2];  // [buf][A 16KB | B 16KB]
  const int tid = threadIdx.x;
  const int lane = tid & 63;
  const int w = tid >> 6;
  const int wr = w >> 1, wc = w & 1;
  const int l15 = lane & 15, l4 = lane >> 4;

  const int rowA0 = blockIdx.x * BM;
  const int colB0 = blockIdx.y * BN;

  f32x4 acc[4][4] = {};

  const unsigned short* Abase = A + (size_t)rowA0 * K;
  const unsigned short* Bbase = B + (size_t)colB0 * K;

  int a_off[2][4], b_off[2][4];
#pragma unroll
  for (int kk = 0; kk < 2; ++kk)
#pragma unroll
    for (int m = 0; m < 4; ++m) {
      int row = wr * 64 + m * 16 + l15;
      int g = kk * 4 + l4;
      a_off[kk][m] = row * 128 + ((g ^ (row & 7)) * 16);
      int rowb = wc * 64 + m * 16 + l15;
      b_off[kk][m] = rowb * 128 + ((g ^ (rowb & 7)) * 16);
    }

  const int NT = K / BK;
  stage128x64(Abase, K, &lds[0][0], tid);
  stage128x64(Bbase, K, &lds[0][BM * BK * 2], tid);
  asm volatile("s_waitcnt vmcnt(0)" ::: "memory");
  __syncthreads();

  int buf = 0;
  for (int t = 0; t < NT; ++t) {
    if (t + 1 < NT) {
      stage128x64(Abase + (t + 1) * BK, K, &lds[buf ^ 1][0], tid);
      stage128x64(Bbase + (t + 1) * BK, K, &lds[buf ^ 1][BM * BK * 2], tid);
    }
    const char* aLds = &lds[buf][0];
    const char* bLds = &lds[buf][BM * BK * 2];
#pragma unroll
    for (int kk = 0; kk < 2; ++kk) {
      bf16x8 af[4], bfv[4];
#pragma unroll
      for (int m = 0; m < 4; ++m) af[m] = *reinterpret_cast<const bf16x8*>(aLds + a_off[kk][m]);
#pragma unroll
      for (int n = 0; n < 4; ++n) bfv[n] = *reinterpret_cast<const bf16x8*>(bLds + b_off[kk][n]);
#pragma unroll
      for (int m = 0; m < 4; ++m)
#pragma unroll
        for (int n = 0; n < 4; ++n)
          acc[m][n] = __builtin_amdgcn_mfma_f32_16x16x32_bf16(af[m], bfv[n], acc[m][n], 0, 0, 0);
    }
    asm volatile("s_waitcnt vmcnt(0)" ::: "memory");
    __syncthreads();
    buf ^= 1;
  }

#pragma unroll
  for (int m = 0; m < 4; ++m) {
#pragma unroll
    for (int r = 0; r < 4; ++r) {
      int row = rowA0 + wr * 64 + m * 16 + l4 * 4 + r;
#pragma unroll
      for (int n = 0; n < 4; ++n) {
        int col = colB0 + wc * 64 + n * 16 + l15;
        if (OUTF32)
          reinterpret_cast<float*>(Cout)[(size_t)row * N + col] = acc[m][n][r];
        else
          reinterpret_cast<unsigned short*>(Cout)[(size_t)row * N + col] = f2bf(acc[m][n][r]);
      }
    }
  }
}

// ---------------- causal flash attention ----------------
// Round-8 (verified PASS) dataflow. Two deltas:
//  1) triangle pairing: block i owns group A = qblock i, group B = qblock 31-i
//     -> every block does exactly 33 tile-bodies (load balance; was 3..63).
//  2) V LDS swizzle gains a (row>>3) term: phys = gq ^ (row&7) ^ ((row>>3)&7)
//     -> V-transpose scalar writes spread over all 32 banks (was 4 banks,
//        16-way). PV reads use matching voff; K keeps old koff.
__global__ __launch_bounds__(256)
void attn(const unsigned short* __restrict__ Q, const unsigned short* __restrict__ Kmat,
          const unsigned short* __restrict__ V, unsigned short* __restrict__ O) {
  __shared__ char smem[24576];  // Ks 8KB | VsL 8KB | Pw 4x2KB
  const int tid = threadIdx.x, lane = tid & 63, w = tid >> 6;
  const int l15 = lane & 15, l4 = lane >> 4;
  const int i = blockIdx.x;             // [0, 16): pair index
  const int bh = blockIdx.y;
  const int b = bh >> 4, h = bh & 15;
  const size_t bT = (size_t)b * TT;
  const int q0A = i * 64 + w * 16;          // group A: qblock i
  const int q0B = (31 - i) * 64 + w * 16;   // group B: qblock 31-i
  const int lastA = i;                      // A's diagonal tile
  const int lastB = 31 - i;                 // B's diagonal tile (= loop bound)

  char* Ks = smem;
  char* VsL = smem + 8192;
  char* Pw = smem + 16384 + w * 2048;

  // Q fragments (A-operand): row = l15, k = kk*32 + l4*8 + j
  const unsigned short* qpA = Q + (bT + q0A + l15) * CC + h * HD;
  const unsigned short* qpB = Q + (bT + q0B + l15) * CC + h * HD;
  bf16x8 qfA[2], qfB[2];
  qfA[0] = *reinterpret_cast<const bf16x8*>(qpA + l4 * 8);
  qfA[1] = *reinterpret_cast<const bf16x8*>(qpA + 32 + l4 * 8);
  qfB[0] = *reinterpret_cast<const bf16x8*>(qpB + l4 * 8);
  qfB[1] = *reinterpret_cast<const bf16x8*>(qpB + 32 + l4 * 8);

  f32x4 oA[4] = {}, oB[4] = {};
  float mA[4], lA[4], mB[4], lB[4];
#pragma unroll
  for (int r = 0; r < 4; ++r) {
    mA[r] = -1e30f; lA[r] = 0.f; mB[r] = -1e30f; lB[r] = 0.f;
  }

  int koff[4][2], voff[4][2], poff[2];
#pragma unroll
  for (int n = 0; n < 4; ++n)
#pragma unroll
    for (int kk = 0; kk < 2; ++kk) {
      int row = n * 16 + l15;
      int g = kk * 4 + l4;
      koff[n][kk] = row * 128 + ((g ^ (row & 7)) * 16);
      voff[n][kk] = row * 128 + ((g ^ (row & 7) ^ ((row >> 3) & 7)) * 16);
    }
#pragma unroll
  for (int kk = 0; kk < 2; ++kk) {
    int row = l15;
    int g = kk * 4 + l4;
    poff[kk] = row * 128 + ((g ^ (row & 7)) * 16);
  }

  const float sc = 0.125f;          // HD^-0.5
  const float LOG2E = 1.44269504f;

  // verified per-tile body (round-2/8 math), parameterized on group state.
#define TILE_BODY(QF, OO, MR, LR, Q0, ISDIAG, KB0)                               \
  {                                                                              \
    f32x4 s_[4] = {};                                                            \
    _Pragma("unroll")                                                            \
    for (int n = 0; n < 4; ++n)                                                  \
      _Pragma("unroll")                                                          \
      for (int kk = 0; kk < 2; ++kk) {                                           \
        bf16x8 kf = *reinterpret_cast<const bf16x8*>(Ks + koff[n][kk]);          \
        s_[n] = __builtin_amdgcn_mfma_f32_16x16x32_bf16(QF[kk], kf, s_[n], 0, 0, 0); \
      }                                                                          \
    if (ISDIAG) {                                                                \
      _Pragma("unroll")                                                          \
      for (int n = 0; n < 4; ++n) {                                              \
        int key = (KB0) + n * 16 + l15;                                          \
        _Pragma("unroll")                                                        \
        for (int r = 0; r < 4; ++r) {                                            \
          int q = (Q0) + l4 * 4 + r;                                             \
          if (key > q) s_[n][r] = -1e30f;                                        \
        }                                                                        \
      }                                                                          \
    }                                                                            \
    float tm_[4];                                                                \
    _Pragma("unroll")                                                            \
    for (int r = 0; r < 4; ++r)                                                  \
      tm_[r] = fmaxf(fmaxf(s_[0][r], s_[1][r]), fmaxf(s_[2][r], s_[3][r]));      \
    _Pragma("unroll")                                                            \
    for (int off = 1; off < 16; off <<= 1)                                       \
      _Pragma("unroll")                                                          \
      for (int r = 0; r < 4; ++r) tm_[r] = fmaxf(tm_[r], __shfl_xor(tm_[r], off, 64)); \
    float mnew_[4], alpha_[4];                                                   \
    _Pragma("unroll")                                                            \
    for (int r = 0; r < 4; ++r) {                                                \
      mnew_[r] = fmaxf(MR[r], tm_[r] * sc);                                      \
      alpha_[r] = exp2f((MR[r] - mnew_[r]) * LOG2E);                             \
      MR[r] = mnew_[r];                                                          \
    }                                                                            \
    float ts_[4] = {0.f, 0.f, 0.f, 0.f};                                         \
    _Pragma("unroll")                                                            \
    for (int n = 0; n < 4; ++n)                                                  \
      _Pragma("unroll")                                                          \
      for (int r = 0; r < 4; ++r) {                                              \
        float p = exp2f((s_[n][r] * sc - mnew_[r]) * LOG2E);                     \
        s_[n][r] = p;                                                            \
        ts_[r] += p;                                                             \
      }                                                                          \
    _Pragma("unroll")                                                            \
    for (int off = 1; off < 16; off <<= 1)                                       \
      _Pragma("unroll")                                                          \
      for (int r = 0; r < 4; ++r) ts_[r] += __shfl_xor(ts_[r], off, 64);         \
    _Pragma("unroll")                                                            \
    for (int r = 0; r < 4; ++r) LR[r] = LR[r] * alpha_[r] + ts_[r];              \
    _Pragma("unroll")                                                            \
    for (int nf2 = 0; nf2 < 4; ++nf2)                                            \
      _Pragma("unroll")                                                          \
      for (int r = 0; r < 4; ++r) OO[nf2][r] *= alpha_[r];                       \
    _Pragma("unroll")                                                            \
    for (int n = 0; n < 4; ++n)                                                  \
      _Pragma("unroll")                                                          \
      for (int r = 0; r < 4; ++r) {                                              \
        int row = l4 * 4 + r;                                                    \
        int col = n * 16 + l15;                                                  \
        int gq = col >> 3;                                                       \
        int off = row * 128 + ((gq ^ (row & 7)) * 16) + (col & 7) * 2;           \
        *reinterpret_cast<__bf16*>(Pw + off) = (__bf16)s_[n][r];                 \
      }                                                                          \
    asm volatile("s_waitcnt lgkmcnt(0)" ::: "memory");                           \
    __builtin_amdgcn_sched_barrier(0);                                           \
    _Pragma("unroll")                                                            \
    for (int kk = 0; kk < 2; ++kk) {                                             \
      bf16x8 pf = *reinterpret_cast<const bf16x8*>(Pw + poff[kk]);               \
      _Pragma("unroll")                                                          \
      for (int nf2 = 0; nf2 < 4; ++nf2) {                                        \
        bf16x8 vf = *reinterpret_cast<const bf16x8*>(VsL + voff[nf2][kk]);       \
        OO[nf2] = __builtin_amdgcn_mfma_f32_16x16x32_bf16(pf, vf, OO[nf2], 0, 0, 0); \
      }                                                                          \
    }                                                                            \
  }

  for (int t = 0; t <= lastB; ++t) {
    const int kb0 = t * 64;
    __syncthreads();  // prior iteration done reading Ks/VsL
    // stage K tile [64 keys][64 d], swizzled source, linear dest (verified)
#pragma unroll
    for (int it = 0; it < 2; ++it) {
      int j = it * 256 + tid;
      int row = j >> 3;
      int lg = (j & 7) ^ (row & 7);
      const unsigned short* g = Kmat + (bT + kb0 + row) * CC + h * HD + lg * 8;
      gload_lds16(g, Ks + j * 16);
    }
    // stage V transposed in-kernel (verified path) with bank-spread swizzle:
    // phys group = gq ^ (row&7) ^ ((row>>3)&7) -> writes cover all 32 banks.
#pragma unroll
    for (int it = 0; it < 2; ++it) {
      int j = it * 256 + tid;
      int key = j >> 3;
      int d0 = (j & 7) * 8;
      bf16x8 vv = *reinterpret_cast<const bf16x8*>(V + (bT + kb0 + key) * CC + h * HD + d0);
#pragma unroll
      for (int jj = 0; jj < 8; ++jj) {
        int row = d0 + jj;
        int gq = key >> 3;
        int off = row * 128 + ((gq ^ (row & 7) ^ ((row >> 3) & 7)) * 16) + (key & 7) * 2;
        *reinterpret_cast<__bf16*>(VsL + off) = vv[jj];
      }
    }
    asm volatile("s_waitcnt vmcnt(0)" ::: "memory");
    __syncthreads();

    if (t <= lastA) {  // wave-uniform guard, outside barriers
      TILE_BODY(qfA, oA, mA, lA, q0A, (t == lastA), kb0)
    }
    TILE_BODY(qfB, oB, mB, lB, q0B, (t == lastB), kb0)
  }
#undef TILE_BODY

  // epilogue: O[b,q, h*64+d] bf16, both groups
#pragma unroll
  for (int nf2 = 0; nf2 < 4; ++nf2)
#pragma unroll
    for (int r = 0; r < 4; ++r) {
      int col = h * HD + nf2 * 16 + l15;
      int qA = q0A + l4 * 4 + r;
      O[(bT + qA) * CC + col] = f2bf(oA[nf2][r] / lA[r]);
      int qB = q0B + l4 * 4 + r;
      O[(bT + qB) * CC + col] = f2bf(oB[nf2][r] / lB[r]);
    }
}

// ---------------- launch ----------------
extern "C" void kernel_launch(void* const* d_in, const int* in_sizes, int n_in,
                              void* d_out, int out_size, void* d_ws, size_t ws_size,
                              hipStream_t stream) {
  const float* x  = (const float*)d_in[0];
  const float* Wq = (const float*)d_in[1];
  const float* Wk = (const float*)d_in[2];
  const float* Wv = (const float*)d_in[3];
  const float* Wo = (const float*)d_in[4];

  char* ws = (char*)d_ws;
  const size_t NX = (size_t)4 * TT * CC;       // 8388608
  const size_t NW = (size_t)CC * CC;           // 1048576
  unsigned short* xb  = (unsigned short*)(ws);
  unsigned short* qb  = (unsigned short*)(ws + 1 * NX * 2);
  unsigned short* kb  = (unsigned short*)(ws + 2 * NX * 2);
  unsigned short* vb  = (unsigned short*)(ws + 3 * NX * 2);
  unsigned short* ob  = (unsigned short*)(ws + 4 * NX * 2);
  unsigned short* wqb = (unsigned short*)(ws + 5 * NX * 2);
  unsigned short* wkb = (unsigned short*)(ws + 5 * NX * 2 + 1 * NW * 2);
  unsigned short* wvb = (unsigned short*)(ws + 5 * NX * 2 + 2 * NW * 2);
  unsigned short* wob = (unsigned short*)(ws + 5 * NX * 2 + 3 * NW * 2);

  castk<<<(int)(NX / 1024), 256, 0, stream>>>(x, xb, (int)NX);
  castk<<<(int)(NW / 1024), 256, 0, stream>>>(Wq, wqb, (int)NW);
  castk<<<(int)(NW / 1024), 256, 0, stream>>>(Wk, wkb, (int)NW);
  castk<<<(int)(NW / 1024), 256, 0, stream>>>(Wv, wvb, (int)NW);
  castk<<<(int)(NW / 1024), 256, 0, stream>>>(Wo, wob, (int)NW);

  dim3 gg(8192 / BM, CC / BN);  // 64 x 8
  gemm_bt<0><<<gg, 256, 0, stream>>>(xb, wqb, qb, 8192, CC, CC);
  gemm_bt<0><<<gg, 256, 0, stream>>>(xb, wkb, kb, 8192, CC, CC);
  gemm_bt<0><<<gg, 256, 0, stream>>>(xb, wvb, vb, 8192, CC, CC);

  attn<<<dim3(16, 4 * HH), 256, 0, stream>>>(qb, kb, vb, ob);

  gemm_bt<1><<<gg, 256, 0, stream>>>(ob, wob, d_out, 8192, CC, CC);
}